// Round 6
// baseline (1853.156 us; speedup 1.0000x reference)
//
#include <hip/hip_runtime.h>
#include <cstdio>

// Mamba block, MI355X round 5 — dtype fix. Round-4 probes proved ALL inputs
// (and the output) are FLOAT32 (A_log fp32 = [ln1, ln2] at words 0,1), not
// bf16; prior rounds misread fp32 bits as bf16 -> NaN cascade. This round:
// fp32 I/O, bf16 internal GEMM (mfma_f32_16x16x32_bf16, fp32 accum), fp32
// weights converted to bf16 during LDS staging. delta/B/C kept fp32 for scan.

typedef unsigned short u16;
typedef __attribute__((ext_vector_type(8))) __bf16 bf16x8;
typedef __attribute__((ext_vector_type(4))) float floatx4;

#define LSEQ 2048
#define DM 1024
#define DI 2048
#define NST 16
#define DTR 64
#define MROWS 4096  // B * L

__device__ __forceinline__ float b2f(u16 v) {
  return __uint_as_float(((unsigned)v) << 16);
}
__device__ __forceinline__ u16 f2b(float f) {
  unsigned b = __float_as_uint(f);
  unsigned r = (b + 0x7FFFu + ((b >> 16) & 1u)) >> 16;
  return (u16)r;
}
__device__ __forceinline__ float sanit(float v) {
  if (isnan(v)) return 0.f;
  if (isinf(v)) return v > 0.f ? 1e4f : -1e4f;
  return v;
}
__device__ __forceinline__ float sigm(float x) { return 1.f / (1.f + __expf(-x)); }
__device__ __forceinline__ float splus(float x) {
  return x > 20.f ? x : log1pf(__expf(x));
}

// ---------------- LayerNorm (fp32 in) -> xn bf16 -----------------------------
__global__ __launch_bounds__(256) void ln_kernel(const float* x, const float* g,
                                                 const float* bia, u16* xn) {
  const int row = blockIdx.x;
  const int c0 = threadIdx.x * 4;
  float4 xv = *(const float4*)(x + (size_t)row * DM + c0);
  float v0 = sanit(xv.x), v1 = sanit(xv.y), v2 = sanit(xv.z), v3 = sanit(xv.w);
  float s = v0 + v1 + v2 + v3;
  float q = v0 * v0 + v1 * v1 + v2 * v2 + v3 * v3;
  for (int off = 32; off > 0; off >>= 1) {
    s += __shfl_down(s, off);
    q += __shfl_down(q, off);
  }
  __shared__ float ss[4], qq[4];
  const int wv = threadIdx.x >> 6, lane = threadIdx.x & 63;
  if (lane == 0) { ss[wv] = s; qq[wv] = q; }
  __syncthreads();
  s = ss[0] + ss[1] + ss[2] + ss[3];
  q = qq[0] + qq[1] + qq[2] + qq[3];
  const float mu = s * (1.f / DM);
  const float inv = rsqrtf(q * (1.f / DM) - mu * mu + 1e-5f);
  float4 gv = *(const float4*)(g + c0);
  float4 bv = *(const float4*)(bia + c0);
  u16* orow = xn + (size_t)row * DM + c0;
  orow[0] = f2b((v0 - mu) * inv * gv.x + bv.x);
  orow[1] = f2b((v1 - mu) * inv * gv.y + bv.y);
  orow[2] = f2b((v2 - mu) * inv * gv.z + bv.z);
  orow[3] = f2b((v3 - mu) * inv * gv.w + bv.w);
}

// ------------- causal depthwise conv (width 4, fp32 w/b) + SiLU --------------
__global__ __launch_bounds__(256) void conv_kernel(const u16* u, const float* w,
                                                   const float* cb, u16* uc) {
  const int idx = blockIdx.x * 256 + threadIdx.x;  // m*DI + d
  const int d = idx & (DI - 1);
  const int m = idx >> 11;
  const int t = m & (LSEQ - 1);
  float acc = cb[d];
  for (int j = 0; j < 4; ++j) {
    int tt = t - 3 + j;
    if (tt >= 0) acc += w[d * 4 + j] * b2f(u[(size_t)(m - 3 + j) * DI + d]);
  }
  acc = acc * sigm(acc);
  uc[idx] = f2b(acc);
}

// -- C = A(M,K;bf16) * B(N,K;fp32->bf16)^T, 64x64 tile, mfma 16x16x32 bf16 ----
// epi 0: in_proj  -> p0=u bf16 (n<DI), p1=z bf16
// epi 1: x_proj   -> p0=dtb bf16 (n<64), pf=bc fp32 (64<=n<96)
// epi 2: dt_proj  -> pf=delta fp32 = softplus(acc + extraf[n])
// epi 3: out_proj -> pf=dout fp32 = sanit(sanit(acc) + sanit(extraf[m*DM+n]))
__global__ __launch_bounds__(256) void gemm_bt(const u16* A, const float* Bw,
                                               int N, int K, int epi, u16* p0,
                                               u16* p1, float* pf,
                                               const float* extraf) {
  __shared__ u16 As[64 * 40];  // LDT=40: +8 pad keeps 16B rows, breaks banks
  __shared__ u16 Bs[64 * 40];
  const int tid = threadIdx.x;
  const int lane = tid & 63;
  const int wm = (tid >> 6) >> 1, wn = (tid >> 6) & 1;
  const int quad = lane >> 4;
  const int l16 = lane & 15;
  const int row0 = blockIdx.x * 64, col0 = blockIdx.y * 64;
  const int lr = tid >> 2;
  const int lc = (tid & 3) * 8;

  floatx4 acc[2][2];
  for (int i = 0; i < 2; ++i)
    for (int j = 0; j < 2; ++j)
      for (int r = 0; r < 4; ++r) acc[i][j][r] = 0.f;

  for (int k0 = 0; k0 < K; k0 += 32) {
    // A: 8 bf16 = 16B
    uint4 av = *(const uint4*)(A + (size_t)(row0 + lr) * K + k0 + lc);
    // B: 8 fp32 = 32B, convert to bf16
    float4 bf0 = {0.f, 0.f, 0.f, 0.f}, bf1 = {0.f, 0.f, 0.f, 0.f};
    const int brow = col0 + lr;
    if (brow < N) {
      const float* bp = Bw + (size_t)brow * K + k0 + lc;
      bf0 = *(const float4*)(bp);
      bf1 = *(const float4*)(bp + 4);
    }
    u16 bw[8] = {f2b(bf0.x), f2b(bf0.y), f2b(bf0.z), f2b(bf0.w),
                 f2b(bf1.x), f2b(bf1.y), f2b(bf1.z), f2b(bf1.w)};
    __syncthreads();
    *(uint4*)&As[lr * 40 + lc] = av;
    *(uint4*)&Bs[lr * 40 + lc] = *(const uint4*)bw;
    __syncthreads();
    bf16x8 a0 = *(const bf16x8*)&As[(wm * 32 + l16) * 40 + quad * 8];
    bf16x8 a1 = *(const bf16x8*)&As[(wm * 32 + 16 + l16) * 40 + quad * 8];
    bf16x8 b0 = *(const bf16x8*)&Bs[(wn * 32 + l16) * 40 + quad * 8];
    bf16x8 b1 = *(const bf16x8*)&Bs[(wn * 32 + 16 + l16) * 40 + quad * 8];
    acc[0][0] = __builtin_amdgcn_mfma_f32_16x16x32_bf16(a0, b0, acc[0][0], 0, 0, 0);
    acc[0][1] = __builtin_amdgcn_mfma_f32_16x16x32_bf16(a0, b1, acc[0][1], 0, 0, 0);
    acc[1][0] = __builtin_amdgcn_mfma_f32_16x16x32_bf16(a1, b0, acc[1][0], 0, 0, 0);
    acc[1][1] = __builtin_amdgcn_mfma_f32_16x16x32_bf16(a1, b1, acc[1][1], 0, 0, 0);
  }

  for (int i = 0; i < 2; ++i)
    for (int j = 0; j < 2; ++j)
      for (int r = 0; r < 4; ++r) {
        const int m = row0 + wm * 32 + i * 16 + quad * 4 + r;
        const int n = col0 + wn * 32 + j * 16 + l16;
        const float val = acc[i][j][r];
        if (epi == 0) {
          if (n < DI)
            p0[(size_t)m * DI + n] = f2b(val);
          else
            p1[(size_t)m * DI + (n - DI)] = f2b(val);
        } else if (epi == 1) {
          if (n < DTR)
            p0[(size_t)m * DTR + n] = f2b(val);
          else if (n < DTR + 2 * NST)
            pf[(size_t)m * (2 * NST) + (n - DTR)] = val;
        } else if (epi == 2) {
          pf[(size_t)m * DI + n] = splus(val + extraf[n]);
        } else {
          float v2 = sanit(val) + sanit(extraf[(size_t)m * DM + n]);
          pf[(size_t)m * DM + n] = sanit(v2);
        }
      }
}

// ---------------- selective scan: 16 lanes (one per n) per (b,d) -------------
__global__ __launch_bounds__(256) void scan_kernel(
    const float* delta, const u16* uc, const float* bc, const u16* zb,
    const float* A_log, const float* D_skip, u16* y) {
  const int tid = blockIdx.x * 256 + threadIdx.x;
  const int n = tid & (NST - 1);
  const int group = tid >> 4;  // b*DI + d
  const int b = group >> 11;
  const int d = group & (DI - 1);
  const float An = -__expf(A_log[d * NST + n]);
  const float Dsk = D_skip[d];
  float h = 0.f;
  const size_t mbase = (size_t)b * LSEQ;
  for (int t = 0; t < LSEQ; ++t) {
    const size_t m = mbase + t;
    const float dv = delta[m * DI + d];
    const float uv = b2f(uc[m * DI + d]);
    const float Bn = bc[m * (2 * NST) + n];
    const float Cn = bc[m * (2 * NST) + NST + n];
    const float dA = __expf(dv * An);
    h = fmaf(dA, h, dv * uv * Bn);
    float p = Cn * h;
    p += __shfl_xor(p, 1);
    p += __shfl_xor(p, 2);
    p += __shfl_xor(p, 4);
    p += __shfl_xor(p, 8);
    if (n == 0) {
      const float zv = b2f(zb[m * DI + d]);
      y[m * DI + d] = f2b((p + uv * Dsk) * (zv * sigm(zv)));
    }
  }
}

#define CK(tag)                                                              \
  do {                                                                       \
    hipError_t e_ = hipGetLastError();                                       \
    if (e_ != hipSuccess)                                                    \
      fprintf(stderr, "[kl] %s err=%d %s\n", tag, (int)e_,                   \
              hipGetErrorString(e_));                                        \
  } while (0)

extern "C" __attribute__((visibility("default"))) void kernel_launch(
    void* const* d_in, const int* in_sizes, int n_in, void* d_out,
    int out_size, void* d_ws, size_t ws_size, hipStream_t stream) {
  const float* x = (const float*)d_in[0];
  const float* ln_g = (const float*)d_in[1];
  const float* ln_b = (const float*)d_in[2];
  const float* in_proj_w = (const float*)d_in[3];    // [2*DI][DM]
  const float* conv_w = (const float*)d_in[4];       // [DI][1][4]
  const float* conv_b = (const float*)d_in[5];       // [DI]
  const float* x_proj_w = (const float*)d_in[6];     // [96][DI]
  const float* dt_proj_w = (const float*)d_in[7];    // [DI][DTR]
  const float* dt_proj_b = (const float*)d_in[8];    // [DI]
  const float* A_log = (const float*)d_in[9];        // [DI][16]
  const float* D_skip = (const float*)d_in[10];      // [DI]
  const float* out_proj_w = (const float*)d_in[11];  // [DM][DI]
  float* dout = (float*)d_out;

  // workspace (~89.5 MB of the 256 MB provided):
  const size_t MBB = 1048576;
  char* ws = (char*)d_ws;
  u16* xn = (u16*)(ws);                     // bf16 [4096][1024]   8 MB
  u16* u = (u16*)(ws + 8 * MBB);            // bf16 [4096][2048]  16 MB
  u16* z = (u16*)(ws + 24 * MBB);           // bf16 [4096][2048]  16 MB
  u16* uc = (u16*)(ws + 40 * MBB);          // bf16 [4096][2048]  16 MB
  u16* dtb = (u16*)(ws + 56 * MBB);         // bf16 [4096][64]    0.5 MB
  float* bc = (float*)(ws + 57 * MBB);      // f32  [4096][32]    0.5 MB
  float* delta = (float*)(ws + 58 * MBB);   // f32  [4096][2048]  32 MB
  u16* y = z;  // scan reads z[m,d] then writes y[m,d] in the same thread

  ln_kernel<<<MROWS, 256, 0, stream>>>(x, ln_g, ln_b, xn);
  CK("ln");
  gemm_bt<<<dim3(MROWS / 64, (2 * DI) / 64), 256, 0, stream>>>(
      xn, in_proj_w, 2 * DI, DM, 0, u, z, nullptr, nullptr);
  CK("in_proj");
  conv_kernel<<<(MROWS * DI) / 256, 256, 0, stream>>>(u, conv_w, conv_b, uc);
  CK("conv");
  gemm_bt<<<dim3(MROWS / 64, 2), 256, 0, stream>>>(
      uc, x_proj_w, DTR + 2 * NST, DI, 1, dtb, nullptr, bc, nullptr);
  CK("x_proj");
  gemm_bt<<<dim3(MROWS / 64, DI / 64), 256, 0, stream>>>(
      dtb, dt_proj_w, DI, DTR, 2, nullptr, nullptr, delta, dt_proj_b);
  CK("dt_proj");
  scan_kernel<<<(MROWS * NST) / 256, 256, 0, stream>>>(delta, uc, bc, z, A_log,
                                                       D_skip, y);
  CK("scan");
  gemm_bt<<<dim3(MROWS / 64, DM / 64), 256, 0, stream>>>(
      y, out_proj_w, DM, DI, 3, nullptr, nullptr, dout, x);
  CK("out_proj");

  // light diagnostics (correctness call only; skipped under graph capture)
  hipStreamCaptureStatus cs = hipStreamCaptureStatusNone;
  hipStreamIsCapturing(stream, &cs);
  if (cs == hipStreamCaptureStatusNone) {
    static float hb[4];
    hipError_t rs = hipStreamSynchronize(stream);
    hipMemcpyAsync(hb, dout, 16, hipMemcpyDeviceToHost, stream);
    hipStreamSynchronize(stream);
    fprintf(stderr, "[kl] sync=%d dout f32: %.5g %.5g %.5g %.5g\n", (int)rs,
            hb[0], hb[1], hb[2], hb[3]);
    fflush(stderr);
  }
}

// Round 7
// 658.262 us; speedup vs baseline: 2.8152x; 2.8152x over previous
//
#include <hip/hip_runtime.h>
#include <cstdio>

// Mamba block, MI355X round 6 — chunked parallel scan.
// Round 5 passed (absmax .0156) at 1853 us, with scan_kernel = 1502 us at 12%
// occupancy / 9.6% VALUBusy (4 waves/CU, 2048 serial iters, latency-bound).
// Fix: linear-recurrence chunking. L=2048 -> 32 chunks x 64. Phase 1 stores
// per-chunk decay product P and local state S (h0=0). Phase 3 folds the
// cross-chunk prefix (<=31 fmas from L2-resident P/S) then rescans its chunk
// emitting gated y. 32x thread parallelism -> occupancy-limited becomes
// compute-bound (~60-120 us). GEMM pipeline unchanged from round 5.

typedef unsigned short u16;
typedef __attribute__((ext_vector_type(8))) __bf16 bf16x8;
typedef __attribute__((ext_vector_type(4))) float floatx4;

#define LSEQ 2048
#define DM 1024
#define DI 2048
#define NST 16
#define DTR 64
#define MROWS 4096  // B * L
#define NC 32       // chunks per sequence
#define CH 64       // chunk length (NC*CH == LSEQ)

__device__ __forceinline__ float b2f(u16 v) {
  return __uint_as_float(((unsigned)v) << 16);
}
__device__ __forceinline__ u16 f2b(float f) {
  unsigned b = __float_as_uint(f);
  unsigned r = (b + 0x7FFFu + ((b >> 16) & 1u)) >> 16;
  return (u16)r;
}
__device__ __forceinline__ float sanit(float v) {
  if (isnan(v)) return 0.f;
  if (isinf(v)) return v > 0.f ? 1e4f : -1e4f;
  return v;
}
__device__ __forceinline__ float sigm(float x) { return 1.f / (1.f + __expf(-x)); }
__device__ __forceinline__ float splus(float x) {
  return x > 20.f ? x : log1pf(__expf(x));
}

// ---------------- LayerNorm (fp32 in) -> xn bf16 -----------------------------
__global__ __launch_bounds__(256) void ln_kernel(const float* x, const float* g,
                                                 const float* bia, u16* xn) {
  const int row = blockIdx.x;
  const int c0 = threadIdx.x * 4;
  float4 xv = *(const float4*)(x + (size_t)row * DM + c0);
  float v0 = sanit(xv.x), v1 = sanit(xv.y), v2 = sanit(xv.z), v3 = sanit(xv.w);
  float s = v0 + v1 + v2 + v3;
  float q = v0 * v0 + v1 * v1 + v2 * v2 + v3 * v3;
  for (int off = 32; off > 0; off >>= 1) {
    s += __shfl_down(s, off);
    q += __shfl_down(q, off);
  }
  __shared__ float ss[4], qq[4];
  const int wv = threadIdx.x >> 6, lane = threadIdx.x & 63;
  if (lane == 0) { ss[wv] = s; qq[wv] = q; }
  __syncthreads();
  s = ss[0] + ss[1] + ss[2] + ss[3];
  q = qq[0] + qq[1] + qq[2] + qq[3];
  const float mu = s * (1.f / DM);
  const float inv = rsqrtf(q * (1.f / DM) - mu * mu + 1e-5f);
  float4 gv = *(const float4*)(g + c0);
  float4 bv = *(const float4*)(bia + c0);
  u16* orow = xn + (size_t)row * DM + c0;
  orow[0] = f2b((v0 - mu) * inv * gv.x + bv.x);
  orow[1] = f2b((v1 - mu) * inv * gv.y + bv.y);
  orow[2] = f2b((v2 - mu) * inv * gv.z + bv.z);
  orow[3] = f2b((v3 - mu) * inv * gv.w + bv.w);
}

// ------------- causal depthwise conv (width 4, fp32 w/b) + SiLU --------------
__global__ __launch_bounds__(256) void conv_kernel(const u16* u, const float* w,
                                                   const float* cb, u16* uc) {
  const int idx = blockIdx.x * 256 + threadIdx.x;  // m*DI + d
  const int d = idx & (DI - 1);
  const int m = idx >> 11;
  const int t = m & (LSEQ - 1);
  float acc = cb[d];
  for (int j = 0; j < 4; ++j) {
    int tt = t - 3 + j;
    if (tt >= 0) acc += w[d * 4 + j] * b2f(u[(size_t)(m - 3 + j) * DI + d]);
  }
  acc = acc * sigm(acc);
  uc[idx] = f2b(acc);
}

// -- C = A(M,K;bf16) * B(N,K;fp32->bf16)^T, 64x64 tile, mfma 16x16x32 bf16 ----
__global__ __launch_bounds__(256) void gemm_bt(const u16* A, const float* Bw,
                                               int N, int K, int epi, u16* p0,
                                               u16* p1, float* pf,
                                               const float* extraf) {
  __shared__ u16 As[64 * 40];
  __shared__ u16 Bs[64 * 40];
  const int tid = threadIdx.x;
  const int lane = tid & 63;
  const int wm = (tid >> 6) >> 1, wn = (tid >> 6) & 1;
  const int quad = lane >> 4;
  const int l16 = lane & 15;
  const int row0 = blockIdx.x * 64, col0 = blockIdx.y * 64;
  const int lr = tid >> 2;
  const int lc = (tid & 3) * 8;

  floatx4 acc[2][2];
  for (int i = 0; i < 2; ++i)
    for (int j = 0; j < 2; ++j)
      for (int r = 0; r < 4; ++r) acc[i][j][r] = 0.f;

  for (int k0 = 0; k0 < K; k0 += 32) {
    uint4 av = *(const uint4*)(A + (size_t)(row0 + lr) * K + k0 + lc);
    float4 bf0 = {0.f, 0.f, 0.f, 0.f}, bf1 = {0.f, 0.f, 0.f, 0.f};
    const int brow = col0 + lr;
    if (brow < N) {
      const float* bp = Bw + (size_t)brow * K + k0 + lc;
      bf0 = *(const float4*)(bp);
      bf1 = *(const float4*)(bp + 4);
    }
    u16 bw[8] = {f2b(bf0.x), f2b(bf0.y), f2b(bf0.z), f2b(bf0.w),
                 f2b(bf1.x), f2b(bf1.y), f2b(bf1.z), f2b(bf1.w)};
    __syncthreads();
    *(uint4*)&As[lr * 40 + lc] = av;
    *(uint4*)&Bs[lr * 40 + lc] = *(const uint4*)bw;
    __syncthreads();
    bf16x8 a0 = *(const bf16x8*)&As[(wm * 32 + l16) * 40 + quad * 8];
    bf16x8 a1 = *(const bf16x8*)&As[(wm * 32 + 16 + l16) * 40 + quad * 8];
    bf16x8 b0 = *(const bf16x8*)&Bs[(wn * 32 + l16) * 40 + quad * 8];
    bf16x8 b1 = *(const bf16x8*)&Bs[(wn * 32 + 16 + l16) * 40 + quad * 8];
    acc[0][0] = __builtin_amdgcn_mfma_f32_16x16x32_bf16(a0, b0, acc[0][0], 0, 0, 0);
    acc[0][1] = __builtin_amdgcn_mfma_f32_16x16x32_bf16(a0, b1, acc[0][1], 0, 0, 0);
    acc[1][0] = __builtin_amdgcn_mfma_f32_16x16x32_bf16(a1, b0, acc[1][0], 0, 0, 0);
    acc[1][1] = __builtin_amdgcn_mfma_f32_16x16x32_bf16(a1, b1, acc[1][1], 0, 0, 0);
  }

  for (int i = 0; i < 2; ++i)
    for (int j = 0; j < 2; ++j)
      for (int r = 0; r < 4; ++r) {
        const int m = row0 + wm * 32 + i * 16 + quad * 4 + r;
        const int n = col0 + wn * 32 + j * 16 + l16;
        const float val = acc[i][j][r];
        if (epi == 0) {
          if (n < DI)
            p0[(size_t)m * DI + n] = f2b(val);
          else
            p1[(size_t)m * DI + (n - DI)] = f2b(val);
        } else if (epi == 1) {
          if (n < DTR)
            p0[(size_t)m * DTR + n] = f2b(val);
          else if (n < DTR + 2 * NST)
            pf[(size_t)m * (2 * NST) + (n - DTR)] = val;
        } else if (epi == 2) {
          pf[(size_t)m * DI + n] = splus(val + extraf[n]);
        } else {
          float v2 = sanit(val) + sanit(extraf[(size_t)m * DM + n]);
          pf[(size_t)m * DM + n] = sanit(v2);
        }
      }
}

// -------- chunked scan, phase 1: per-chunk local scan -> P (decay), S --------
// tid = ((b*NC + c)*DI + d)*NST + n  (wave = 4 consecutive d, same chunk)
__global__ __launch_bounds__(256) void scan_p1(const float* delta,
                                               const u16* uc, const float* bc,
                                               const float* A_log, float* Pbuf,
                                               float* Sbuf) {
  const int tid = blockIdx.x * 256 + threadIdx.x;
  const int n = tid & 15;
  const int d = (tid >> 4) & (DI - 1);
  const int c = (tid >> 15) & (NC - 1);
  const int b = tid >> 20;
  const float An = -__expf(A_log[d * NST + n]);
  float h = 0.f, P = 1.f;
  const size_t m0 = (size_t)b * LSEQ + (size_t)c * CH;
  for (int t = 0; t < CH; ++t) {
    const size_t m = m0 + t;
    const float dv = delta[m * DI + d];
    const float uv = b2f(uc[m * DI + d]);
    const float Bn = bc[m * (2 * NST) + n];
    const float dA = __expf(dv * An);
    h = fmaf(dA, h, dv * uv * Bn);
    P *= dA;
  }
  Pbuf[tid] = P;
  Sbuf[tid] = h;
}

// -------- phase 3: fold cross-chunk prefix, rescan chunk, emit gated y -------
__global__ __launch_bounds__(256) void scan_p2(
    const float* delta, const u16* uc, const float* bc, const u16* zb,
    const float* A_log, const float* D_skip, const float* Pbuf,
    const float* Sbuf, u16* y) {
  const int tid = blockIdx.x * 256 + threadIdx.x;
  const int n = tid & 15;
  const int d = (tid >> 4) & (DI - 1);
  const int c = (tid >> 15) & (NC - 1);
  const int b = tid >> 20;
  // h_init = scan of (S,P) over chunks 0..c-1 (ascending: later applied last)
  float h = 0.f;
  const int base = tid - (c << 15);
  for (int cc = 0; cc < c; ++cc) {
    const int idx = base + (cc << 15);
    h = fmaf(Pbuf[idx], h, Sbuf[idx]);
  }
  const float An = -__expf(A_log[d * NST + n]);
  const float Dsk = D_skip[d];
  const size_t m0 = (size_t)b * LSEQ + (size_t)c * CH;
  for (int t = 0; t < CH; ++t) {
    const size_t m = m0 + t;
    const float dv = delta[m * DI + d];
    const float uv = b2f(uc[m * DI + d]);
    const float Bn = bc[m * (2 * NST) + n];
    const float Cn = bc[m * (2 * NST) + NST + n];
    const float dA = __expf(dv * An);
    h = fmaf(dA, h, dv * uv * Bn);
    float p = Cn * h;
    p += __shfl_xor(p, 1);
    p += __shfl_xor(p, 2);
    p += __shfl_xor(p, 4);
    p += __shfl_xor(p, 8);
    if (n == 0) {
      const float zv = b2f(zb[m * DI + d]);
      y[m * DI + d] = f2b((p + uv * Dsk) * (zv * sigm(zv)));
    }
  }
}

#define CK(tag)                                                              \
  do {                                                                       \
    hipError_t e_ = hipGetLastError();                                       \
    if (e_ != hipSuccess)                                                    \
      fprintf(stderr, "[kl] %s err=%d %s\n", tag, (int)e_,                   \
              hipGetErrorString(e_));                                        \
  } while (0)

extern "C" __attribute__((visibility("default"))) void kernel_launch(
    void* const* d_in, const int* in_sizes, int n_in, void* d_out,
    int out_size, void* d_ws, size_t ws_size, hipStream_t stream) {
  const float* x = (const float*)d_in[0];
  const float* ln_g = (const float*)d_in[1];
  const float* ln_b = (const float*)d_in[2];
  const float* in_proj_w = (const float*)d_in[3];    // [2*DI][DM]
  const float* conv_w = (const float*)d_in[4];       // [DI][1][4]
  const float* conv_b = (const float*)d_in[5];       // [DI]
  const float* x_proj_w = (const float*)d_in[6];     // [96][DI]
  const float* dt_proj_w = (const float*)d_in[7];    // [DI][DTR]
  const float* dt_proj_b = (const float*)d_in[8];    // [DI]
  const float* A_log = (const float*)d_in[9];        // [DI][16]
  const float* D_skip = (const float*)d_in[10];      // [DI]
  const float* out_proj_w = (const float*)d_in[11];  // [DM][DI]
  float* dout = (float*)d_out;

  // workspace (~106.5 MB of 256 MB):
  const size_t MBB = 1048576;
  char* ws = (char*)d_ws;
  u16* xn = (u16*)(ws);                    // bf16 [4096][1024]   8 MB
  u16* u = (u16*)(ws + 8 * MBB);           // bf16 [4096][2048]  16 MB
  u16* z = (u16*)(ws + 24 * MBB);          // bf16 [4096][2048]  16 MB
  u16* uc = (u16*)(ws + 40 * MBB);         // bf16 [4096][2048]  16 MB
  u16* dtb = (u16*)(ws + 56 * MBB);        // bf16 [4096][64]    0.5 MB
  float* bc = (float*)(ws + 57 * MBB);     // f32  [4096][32]    0.5 MB
  float* delta = (float*)(ws + 58 * MBB);  // f32  [4096][2048]  32 MB
  float* Pbuf = (float*)(ws + 90 * MBB);   // f32  [2M]           8 MB
  float* Sbuf = (float*)(ws + 98 * MBB);   // f32  [2M]           8 MB
  u16* y = z;  // scan reads z[m,d] then writes y[m,d] in the same thread

  ln_kernel<<<MROWS, 256, 0, stream>>>(x, ln_g, ln_b, xn);
  CK("ln");
  gemm_bt<<<dim3(MROWS / 64, (2 * DI) / 64), 256, 0, stream>>>(
      xn, in_proj_w, 2 * DI, DM, 0, u, z, nullptr, nullptr);
  CK("in_proj");
  conv_kernel<<<(MROWS * DI) / 256, 256, 0, stream>>>(u, conv_w, conv_b, uc);
  CK("conv");
  gemm_bt<<<dim3(MROWS / 64, 2), 256, 0, stream>>>(
      uc, x_proj_w, DTR + 2 * NST, DI, 1, dtb, nullptr, bc, nullptr);
  CK("x_proj");
  gemm_bt<<<dim3(MROWS / 64, DI / 64), 256, 0, stream>>>(
      dtb, dt_proj_w, DI, DTR, 2, nullptr, nullptr, delta, dt_proj_b);
  CK("dt_proj");
  // chunked selective scan: 2 * DI * NST * NC threads = 2M
  const int scan_blocks = (2 * DI * NST * NC) / 256;
  scan_p1<<<scan_blocks, 256, 0, stream>>>(delta, uc, bc, A_log, Pbuf, Sbuf);
  CK("scan_p1");
  scan_p2<<<scan_blocks, 256, 0, stream>>>(delta, uc, bc, z, A_log, D_skip,
                                           Pbuf, Sbuf, y);
  CK("scan_p2");
  gemm_bt<<<dim3(MROWS / 64, DM / 64), 256, 0, stream>>>(
      y, out_proj_w, DM, DI, 3, nullptr, nullptr, dout, x);
  CK("out_proj");
}

// Round 8
// 527.453 us; speedup vs baseline: 3.5134x; 1.2480x over previous
//
#include <hip/hip_runtime.h>
#include <cstdio>

// Mamba block, MI355X round 7 — register-resident scan states.
// Round 6: scan_p2 256 us at VALUBusy 62% = instruction-issue bound. The
// 16-lanes-per-d mapping issues ~16 insts per (n,t) element: 4x redundant
// dv/uv loads, 4 shfl + 4 add for a reduction only lane 0 uses.
// Fix: 1 thread per (b,chunk,d) with n=0..15 in registers (h[16], An[16]).
// Per t: 2 scalar loads + B/C as float4s + 16 exp + 32 fma, reduction
// in-register. NC=64 chunks of CH=32 -> 262K threads, 16 waves/CU, ILP-16.
// P/S buffers in [b,c,d,n] layout (16 contiguous per thread).

typedef unsigned short u16;
typedef __attribute__((ext_vector_type(8))) __bf16 bf16x8;
typedef __attribute__((ext_vector_type(4))) float floatx4;

#define LSEQ 2048
#define DM 1024
#define DI 2048
#define NST 16
#define DTR 64
#define MROWS 4096  // B * L
#define NC 64       // chunks per sequence
#define CH 32       // chunk length (NC*CH == LSEQ)

__device__ __forceinline__ float b2f(u16 v) {
  return __uint_as_float(((unsigned)v) << 16);
}
__device__ __forceinline__ u16 f2b(float f) {
  unsigned b = __float_as_uint(f);
  unsigned r = (b + 0x7FFFu + ((b >> 16) & 1u)) >> 16;
  return (u16)r;
}
__device__ __forceinline__ float sanit(float v) {
  if (isnan(v)) return 0.f;
  if (isinf(v)) return v > 0.f ? 1e4f : -1e4f;
  return v;
}
__device__ __forceinline__ float sigm(float x) { return 1.f / (1.f + __expf(-x)); }
__device__ __forceinline__ float splus(float x) {
  return x > 20.f ? x : log1pf(__expf(x));
}

// ---------------- LayerNorm (fp32 in) -> xn bf16 -----------------------------
__global__ __launch_bounds__(256) void ln_kernel(const float* x, const float* g,
                                                 const float* bia, u16* xn) {
  const int row = blockIdx.x;
  const int c0 = threadIdx.x * 4;
  float4 xv = *(const float4*)(x + (size_t)row * DM + c0);
  float v0 = sanit(xv.x), v1 = sanit(xv.y), v2 = sanit(xv.z), v3 = sanit(xv.w);
  float s = v0 + v1 + v2 + v3;
  float q = v0 * v0 + v1 * v1 + v2 * v2 + v3 * v3;
  for (int off = 32; off > 0; off >>= 1) {
    s += __shfl_down(s, off);
    q += __shfl_down(q, off);
  }
  __shared__ float ss[4], qq[4];
  const int wv = threadIdx.x >> 6, lane = threadIdx.x & 63;
  if (lane == 0) { ss[wv] = s; qq[wv] = q; }
  __syncthreads();
  s = ss[0] + ss[1] + ss[2] + ss[3];
  q = qq[0] + qq[1] + qq[2] + qq[3];
  const float mu = s * (1.f / DM);
  const float inv = rsqrtf(q * (1.f / DM) - mu * mu + 1e-5f);
  float4 gv = *(const float4*)(g + c0);
  float4 bv = *(const float4*)(bia + c0);
  u16* orow = xn + (size_t)row * DM + c0;
  orow[0] = f2b((v0 - mu) * inv * gv.x + bv.x);
  orow[1] = f2b((v1 - mu) * inv * gv.y + bv.y);
  orow[2] = f2b((v2 - mu) * inv * gv.z + bv.z);
  orow[3] = f2b((v3 - mu) * inv * gv.w + bv.w);
}

// ------------- causal depthwise conv (width 4, fp32 w/b) + SiLU --------------
__global__ __launch_bounds__(256) void conv_kernel(const u16* u, const float* w,
                                                   const float* cb, u16* uc) {
  const int idx = blockIdx.x * 256 + threadIdx.x;  // m*DI + d
  const int d = idx & (DI - 1);
  const int m = idx >> 11;
  const int t = m & (LSEQ - 1);
  float acc = cb[d];
  for (int j = 0; j < 4; ++j) {
    int tt = t - 3 + j;
    if (tt >= 0) acc += w[d * 4 + j] * b2f(u[(size_t)(m - 3 + j) * DI + d]);
  }
  acc = acc * sigm(acc);
  uc[idx] = f2b(acc);
}

// -- C = A(M,K;bf16) * B(N,K;fp32->bf16)^T, 64x64 tile, mfma 16x16x32 bf16 ----
__global__ __launch_bounds__(256) void gemm_bt(const u16* A, const float* Bw,
                                               int N, int K, int epi, u16* p0,
                                               u16* p1, float* pf,
                                               const float* extraf) {
  __shared__ u16 As[64 * 40];
  __shared__ u16 Bs[64 * 40];
  const int tid = threadIdx.x;
  const int lane = tid & 63;
  const int wm = (tid >> 6) >> 1, wn = (tid >> 6) & 1;
  const int quad = lane >> 4;
  const int l16 = lane & 15;
  const int row0 = blockIdx.x * 64, col0 = blockIdx.y * 64;
  const int lr = tid >> 2;
  const int lc = (tid & 3) * 8;

  floatx4 acc[2][2];
  for (int i = 0; i < 2; ++i)
    for (int j = 0; j < 2; ++j)
      for (int r = 0; r < 4; ++r) acc[i][j][r] = 0.f;

  for (int k0 = 0; k0 < K; k0 += 32) {
    uint4 av = *(const uint4*)(A + (size_t)(row0 + lr) * K + k0 + lc);
    float4 bf0 = {0.f, 0.f, 0.f, 0.f}, bf1 = {0.f, 0.f, 0.f, 0.f};
    const int brow = col0 + lr;
    if (brow < N) {
      const float* bp = Bw + (size_t)brow * K + k0 + lc;
      bf0 = *(const float4*)(bp);
      bf1 = *(const float4*)(bp + 4);
    }
    u16 bw[8] = {f2b(bf0.x), f2b(bf0.y), f2b(bf0.z), f2b(bf0.w),
                 f2b(bf1.x), f2b(bf1.y), f2b(bf1.z), f2b(bf1.w)};
    __syncthreads();
    *(uint4*)&As[lr * 40 + lc] = av;
    *(uint4*)&Bs[lr * 40 + lc] = *(const uint4*)bw;
    __syncthreads();
    bf16x8 a0 = *(const bf16x8*)&As[(wm * 32 + l16) * 40 + quad * 8];
    bf16x8 a1 = *(const bf16x8*)&As[(wm * 32 + 16 + l16) * 40 + quad * 8];
    bf16x8 b0 = *(const bf16x8*)&Bs[(wn * 32 + l16) * 40 + quad * 8];
    bf16x8 b1 = *(const bf16x8*)&Bs[(wn * 32 + 16 + l16) * 40 + quad * 8];
    acc[0][0] = __builtin_amdgcn_mfma_f32_16x16x32_bf16(a0, b0, acc[0][0], 0, 0, 0);
    acc[0][1] = __builtin_amdgcn_mfma_f32_16x16x32_bf16(a0, b1, acc[0][1], 0, 0, 0);
    acc[1][0] = __builtin_amdgcn_mfma_f32_16x16x32_bf16(a1, b0, acc[1][0], 0, 0, 0);
    acc[1][1] = __builtin_amdgcn_mfma_f32_16x16x32_bf16(a1, b1, acc[1][1], 0, 0, 0);
  }

  for (int i = 0; i < 2; ++i)
    for (int j = 0; j < 2; ++j)
      for (int r = 0; r < 4; ++r) {
        const int m = row0 + wm * 32 + i * 16 + quad * 4 + r;
        const int n = col0 + wn * 32 + j * 16 + l16;
        const float val = acc[i][j][r];
        if (epi == 0) {
          if (n < DI)
            p0[(size_t)m * DI + n] = f2b(val);
          else
            p1[(size_t)m * DI + (n - DI)] = f2b(val);
        } else if (epi == 1) {
          if (n < DTR)
            p0[(size_t)m * DTR + n] = f2b(val);
          else if (n < DTR + 2 * NST)
            pf[(size_t)m * (2 * NST) + (n - DTR)] = val;
        } else if (epi == 2) {
          pf[(size_t)m * DI + n] = splus(val + extraf[n]);
        } else {
          float v2 = sanit(val) + sanit(extraf[(size_t)m * DM + n]);
          pf[(size_t)m * DM + n] = sanit(v2);
        }
      }
}

// ------- chunked scan, phase 1: 1 thread per (b,c,d), n in registers ---------
// P/S layout: [((b*NC+c)*DI+d)*16 + n]  (16 contiguous per thread)
__global__ __launch_bounds__(256) void scan_p1(const float* delta,
                                               const u16* uc, const float* bc,
                                               const float* A_log, float* Pbuf,
                                               float* Sbuf) {
  const int tid = blockIdx.x * 256 + threadIdx.x;  // B*NC*DI = 262144
  const int d = tid & (DI - 1);
  const int c = (tid >> 11) & (NC - 1);
  const int b = tid >> 17;
  float An[NST], h[NST], P[NST];
  {
    const float4* ap = (const float4*)(A_log + d * NST);
#pragma unroll
    for (int j4 = 0; j4 < 4; ++j4) {
      float4 a = ap[j4];
      An[j4 * 4 + 0] = -__expf(a.x);
      An[j4 * 4 + 1] = -__expf(a.y);
      An[j4 * 4 + 2] = -__expf(a.z);
      An[j4 * 4 + 3] = -__expf(a.w);
    }
  }
#pragma unroll
  for (int j = 0; j < NST; ++j) { h[j] = 0.f; P[j] = 1.f; }
  const size_t m0 = (size_t)b * LSEQ + (size_t)c * CH;
  for (int t = 0; t < CH; ++t) {
    const size_t m = m0 + t;
    const float dv = delta[m * DI + d];
    const float du = dv * b2f(uc[m * DI + d]);
    const float4* bp = (const float4*)(bc + m * (2 * NST));
    float4 B0 = bp[0], B1 = bp[1], B2 = bp[2], B3 = bp[3];
    const float Bv[NST] = {B0.x, B0.y, B0.z, B0.w, B1.x, B1.y, B1.z, B1.w,
                           B2.x, B2.y, B2.z, B2.w, B3.x, B3.y, B3.z, B3.w};
#pragma unroll
    for (int j = 0; j < NST; ++j) {
      const float dA = __expf(dv * An[j]);
      h[j] = fmaf(dA, h[j], du * Bv[j]);
      P[j] *= dA;
    }
  }
  float4* Pp = (float4*)(Pbuf + (size_t)tid * NST);
  float4* Sp = (float4*)(Sbuf + (size_t)tid * NST);
#pragma unroll
  for (int j4 = 0; j4 < 4; ++j4) {
    Pp[j4] = {P[j4 * 4], P[j4 * 4 + 1], P[j4 * 4 + 2], P[j4 * 4 + 3]};
    Sp[j4] = {h[j4 * 4], h[j4 * 4 + 1], h[j4 * 4 + 2], h[j4 * 4 + 3]};
  }
}

// ------- phase 2: fold cross-chunk prefix, rescan chunk, emit gated y --------
__global__ __launch_bounds__(256) void scan_p2(
    const float* delta, const u16* uc, const float* bc, const u16* zb,
    const float* A_log, const float* D_skip, const float* Pbuf,
    const float* Sbuf, u16* y) {
  const int tid = blockIdx.x * 256 + threadIdx.x;
  const int d = tid & (DI - 1);
  const int c = (tid >> 11) & (NC - 1);
  const int b = tid >> 17;
  float h[NST];
#pragma unroll
  for (int j = 0; j < NST; ++j) h[j] = 0.f;
  // fold chunks 0..c-1 (ascending)
  const size_t foldbase = ((size_t)b * NC * DI + d) * NST;
  for (int cc = 0; cc < c; ++cc) {
    const float4* Pp = (const float4*)(Pbuf + foldbase + (size_t)cc * DI * NST);
    const float4* Sp = (const float4*)(Sbuf + foldbase + (size_t)cc * DI * NST);
#pragma unroll
    for (int j4 = 0; j4 < 4; ++j4) {
      float4 P = Pp[j4], S = Sp[j4];
      h[j4 * 4 + 0] = fmaf(P.x, h[j4 * 4 + 0], S.x);
      h[j4 * 4 + 1] = fmaf(P.y, h[j4 * 4 + 1], S.y);
      h[j4 * 4 + 2] = fmaf(P.z, h[j4 * 4 + 2], S.z);
      h[j4 * 4 + 3] = fmaf(P.w, h[j4 * 4 + 3], S.w);
    }
  }
  float An[NST];
  {
    const float4* ap = (const float4*)(A_log + d * NST);
#pragma unroll
    for (int j4 = 0; j4 < 4; ++j4) {
      float4 a = ap[j4];
      An[j4 * 4 + 0] = -__expf(a.x);
      An[j4 * 4 + 1] = -__expf(a.y);
      An[j4 * 4 + 2] = -__expf(a.z);
      An[j4 * 4 + 3] = -__expf(a.w);
    }
  }
  const float Dsk = D_skip[d];
  const size_t m0 = (size_t)b * LSEQ + (size_t)c * CH;
  for (int t = 0; t < CH; ++t) {
    const size_t m = m0 + t;
    const float dv = delta[m * DI + d];
    const float uv = b2f(uc[m * DI + d]);
    const float du = dv * uv;
    const float4* bp = (const float4*)(bc + m * (2 * NST));
    float4 B0 = bp[0], B1 = bp[1], B2 = bp[2], B3 = bp[3];
    float4 C0 = bp[4], C1 = bp[5], C2 = bp[6], C3 = bp[7];
    const float Bv[NST] = {B0.x, B0.y, B0.z, B0.w, B1.x, B1.y, B1.z, B1.w,
                           B2.x, B2.y, B2.z, B2.w, B3.x, B3.y, B3.z, B3.w};
    const float Cv[NST] = {C0.x, C0.y, C0.z, C0.w, C1.x, C1.y, C1.z, C1.w,
                           C2.x, C2.y, C2.z, C2.w, C3.x, C3.y, C3.z, C3.w};
    float p = 0.f;
#pragma unroll
    for (int j = 0; j < NST; ++j) {
      const float dA = __expf(dv * An[j]);
      h[j] = fmaf(dA, h[j], du * Bv[j]);
      p = fmaf(Cv[j], h[j], p);
    }
    const float zv = b2f(zb[m * DI + d]);
    y[m * DI + d] = f2b((p + uv * Dsk) * (zv * sigm(zv)));
  }
}

#define CK(tag)                                                              \
  do {                                                                       \
    hipError_t e_ = hipGetLastError();                                       \
    if (e_ != hipSuccess)                                                    \
      fprintf(stderr, "[kl] %s err=%d %s\n", tag, (int)e_,                   \
              hipGetErrorString(e_));                                        \
  } while (0)

extern "C" __attribute__((visibility("default"))) void kernel_launch(
    void* const* d_in, const int* in_sizes, int n_in, void* d_out,
    int out_size, void* d_ws, size_t ws_size, hipStream_t stream) {
  const float* x = (const float*)d_in[0];
  const float* ln_g = (const float*)d_in[1];
  const float* ln_b = (const float*)d_in[2];
  const float* in_proj_w = (const float*)d_in[3];    // [2*DI][DM]
  const float* conv_w = (const float*)d_in[4];       // [DI][1][4]
  const float* conv_b = (const float*)d_in[5];       // [DI]
  const float* x_proj_w = (const float*)d_in[6];     // [96][DI]
  const float* dt_proj_w = (const float*)d_in[7];    // [DI][DTR]
  const float* dt_proj_b = (const float*)d_in[8];    // [DI]
  const float* A_log = (const float*)d_in[9];        // [DI][16]
  const float* D_skip = (const float*)d_in[10];      // [DI]
  const float* out_proj_w = (const float*)d_in[11];  // [DM][DI]
  float* dout = (float*)d_out;

  // workspace (~122.5 MB of 256 MB):
  const size_t MBB = 1048576;
  char* ws = (char*)d_ws;
  u16* xn = (u16*)(ws);                    // bf16 [4096][1024]   8 MB
  u16* u = (u16*)(ws + 8 * MBB);           // bf16 [4096][2048]  16 MB
  u16* z = (u16*)(ws + 24 * MBB);          // bf16 [4096][2048]  16 MB
  u16* uc = (u16*)(ws + 40 * MBB);         // bf16 [4096][2048]  16 MB
  u16* dtb = (u16*)(ws + 56 * MBB);        // bf16 [4096][64]    0.5 MB
  float* bc = (float*)(ws + 57 * MBB);     // f32  [4096][32]    0.5 MB
  float* delta = (float*)(ws + 58 * MBB);  // f32  [4096][2048]  32 MB
  float* Pbuf = (float*)(ws + 90 * MBB);   // f32  [B*NC*DI*16]  16 MB
  float* Sbuf = (float*)(ws + 106 * MBB);  // f32  [B*NC*DI*16]  16 MB
  u16* y = z;  // scan reads z[m,d] then writes y[m,d] in the same thread

  ln_kernel<<<MROWS, 256, 0, stream>>>(x, ln_g, ln_b, xn);
  CK("ln");
  gemm_bt<<<dim3(MROWS / 64, (2 * DI) / 64), 256, 0, stream>>>(
      xn, in_proj_w, 2 * DI, DM, 0, u, z, nullptr, nullptr);
  CK("in_proj");
  conv_kernel<<<(MROWS * DI) / 256, 256, 0, stream>>>(u, conv_w, conv_b, uc);
  CK("conv");
  gemm_bt<<<dim3(MROWS / 64, 2), 256, 0, stream>>>(
      uc, x_proj_w, DTR + 2 * NST, DI, 1, dtb, nullptr, bc, nullptr);
  CK("x_proj");
  gemm_bt<<<dim3(MROWS / 64, DI / 64), 256, 0, stream>>>(
      dtb, dt_proj_w, DI, DTR, 2, nullptr, nullptr, delta, dt_proj_b);
  CK("dt_proj");
  // chunked selective scan: B*NC*DI threads = 262144
  const int scan_blocks = (2 * NC * DI) / 256;
  scan_p1<<<scan_blocks, 256, 0, stream>>>(delta, uc, bc, A_log, Pbuf, Sbuf);
  CK("scan_p1");
  scan_p2<<<scan_blocks, 256, 0, stream>>>(delta, uc, bc, z, A_log, D_skip,
                                           Pbuf, Sbuf, y);
  CK("scan_p2");
  gemm_bt<<<dim3(MROWS / 64, DM / 64), 256, 0, stream>>>(
      y, out_proj_w, DM, DI, 3, nullptr, nullptr, dout, x);
  CK("out_proj");
}